// Round 14
// baseline (477.709 us; speedup 1.0000x reference)
//
#include <hip/hip_runtime.h>
#include <math.h>

#define HID 128
#define LSEQ 1024
#define NB 64  // batch
#define SUB 32           // subchunk length for chunk-parallel scan
#define NQG (LSEQ / SUB) // 32 time-subchunks per direction
#define NCH 16384        // total channels (2 dirs * 64 b * 128 h)

typedef __attribute__((ext_vector_type(4))) float f32x4;
typedef __attribute__((ext_vector_type(8))) short bf16x8;
typedef __attribute__((ext_vector_type(8))) unsigned short u16x8;
typedef __attribute__((ext_vector_type(4))) unsigned short u16x4;

__device__ __forceinline__ unsigned short f2bf(float x) {
    union { float f; unsigned int u; } a; a.f = x;
    unsigned int r = a.u + 0x7FFFu + ((a.u >> 16) & 1u);
    return (unsigned short)(r >> 16);
}
__device__ __forceinline__ float bf2f(unsigned short h) {
    union { float f; unsigned int u; } a; a.u = ((unsigned int)h) << 16;
    return a.f;
}
__device__ __forceinline__ float sigmoidf_(float x) { return 1.0f / (1.0f + __expf(-x)); }
__device__ __forceinline__ float seluf_(float x) {
    const float sc = 1.0507009873554805f, al = 1.6732632423543772f;
    return x > 0.0f ? sc * x : sc * al * (__expf(x) - 1.0f);
}

__device__ __forceinline__ void gload16(const unsigned short* g, unsigned short* l) {
    __builtin_amdgcn_global_load_lds(
        (const __attribute__((address_space(1))) unsigned int*)g,
        (__attribute__((address_space(3))) unsigned int*)l, 16, 0, 0);
}

// W (K x N fp32, N = 2*128*kw) -> Wt plane-major: row n' = dir*128*kw + j*128 + h
__global__ __launch_bounds__(256) void conv_wt(const float* __restrict__ W,
                                               unsigned short* __restrict__ Wt,
                                               int K, int N, int kw) {
    int idx = blockIdx.x * 256 + threadIdx.x;
    if (idx >= K * N) return;
    int k = idx / N, n = idx - k * N;
    const int dir = n / (128 * kw);
    const int rem = n - dir * 128 * kw;
    const int h = rem / kw, j = rem - h * kw;
    const int np = dir * 128 * kw + j * 128 + h;
    Wt[(size_t)np * K + k] = f2bf(W[idx]);
}

__global__ __launch_bounds__(256) void conv_in(const float* __restrict__ in,
                                               unsigned short* __restrict__ outp,
                                               int n4) {
    int idx = blockIdx.x * 256 + threadIdx.x;
    if (idx >= n4) return;
    const float4 v = *reinterpret_cast<const float4*>(in + (size_t)idx * 4);
    u16x4 w;
    w[0] = f2bf(v.x); w[1] = f2bf(v.y); w[2] = f2bf(v.z); w[3] = f2bf(v.w);
    *(u16x4*)(outp + (size_t)idx * 4) = w;
}

// Streaming GEMM v8 = v7 with 4 m-frags/wave (64 rows): same 8 B-ds_reads per
// step now feed 32 MFMA (was 16) — halves LDS bytes/MFMA, the measured binder
// (v7: 10 waves x 8KB / 128B/cy ~ 640cy/round vs 80cy MFMA -> 14.5% MfmaUtil).
// Block = 64-col n-tile, B LDS-resident, 2 m-tiles of 256 rows, A straight to
// VGPRs depth-1 (depth-2 proven null, r13). One barrier total.
template <int K, int NC>
__global__ __launch_bounds__(256, 3) void gemm_v8(const unsigned short* __restrict__ A,
                                                  const unsigned short* __restrict__ Bt,
                                                  unsigned short* __restrict__ C) {
    constexpr int NN = NC / 64;
    constexpr int NT = K / 64;
    constexpr int NSTEP = 2 * NT;  // 2 m-tiles of 256 rows per block
    __shared__ __align__(16) unsigned short smB[NT * 4096];  // 64 cols x K

    const int bid = blockIdx.x;
    const int mi = bid & 7;                 // XCD index
    const int tt = bid >> 3;
    const int n = tt % NN;
    const int mg = (tt / NN) * 8 + mi;
    const int mb = mg * 512;
    const int n0 = n * 64;

    const int tid = threadIdx.x;
    const int w = tid >> 6, l = tid & 63;
    const int rlo = l & 15, g = l >> 4;
    const int kswz = (rlo & 7) * 8;

    // ---- B resident load (once): swizzled k-chunks ----
#pragma unroll
    for (int kt = 0; kt < NT; ++kt)
#pragma unroll
        for (int rd = 0; rd < 2; ++rd) {
            const int col = rd * 32 + (tid >> 3);
            const int kxb = (tid & 7) ^ ((tid >> 3) & 7);
            gload16(Bt + (size_t)(n0 + col) * K + kt * 64 + kxb * 8,
                    &smB[kt * 4096 + rd * 2048 + tid * 8]);
        }

    // per-lane A base: row = mb + w*64 + rlo, k-chunk g*8
    const unsigned short* gA = A + ((size_t)mb + w * 64 + rlo) * K + g * 8;

    bf16x8 af[2][4][2];  // [buf][mf][kk] — static indices after unroll
    auto loadA = [&](int s, int buf) {
        const int mt = s / NT, kt = s % NT;
        const unsigned short* p = gA + (size_t)mt * 256 * K + kt * 64;
#pragma unroll
        for (int mf = 0; mf < 4; ++mf)
#pragma unroll
            for (int kk = 0; kk < 2; ++kk)
                af[buf][mf][kk] = *(const bf16x8*)(p + (size_t)mf * 16 * K + kk * 32);
    };

    loadA(0, 0);
    __syncthreads();  // B resident for all waves (prologue-only full drain)

    f32x4 acc[4][4];
#pragma unroll
    for (int s = 0; s < NSTEP; ++s) {
        const int mt = s / NT, kt = s % NT, cur = s & 1;
        if (kt == 0) {
#pragma unroll
            for (int mf = 0; mf < 4; ++mf)
#pragma unroll
                for (int nf = 0; nf < 4; ++nf) acc[mf][nf] = (f32x4){0.f, 0.f, 0.f, 0.f};
        }
        if (s + 1 < NSTEP) loadA(s + 1, cur ^ 1);  // depth-1 reg prefetch
#pragma unroll
        for (int kk = 0; kk < 2; ++kk) {
            const int koff = (kk * 32 + g * 8) ^ kswz;
            bf16x8 bff[4];
#pragma unroll
            for (int nf = 0; nf < 4; ++nf)
                bff[nf] = *(const bf16x8*)(&smB[kt * 4096 + (nf * 16 + rlo) * 64 + koff]);
#pragma unroll
            for (int mf = 0; mf < 4; ++mf)
#pragma unroll
                for (int nf = 0; nf < 4; ++nf)
                    acc[mf][nf] = __builtin_amdgcn_mfma_f32_16x16x32_bf16(
                        bff[nf], af[cur][mf][kk], acc[mf][nf], 0, 0, 0);  // swapped
        }
        if (kt == NT - 1) {  // lane holds rows ...+rlo, cols nf*16 + g*4 .. +3
            const int rowb = mb + mt * 256 + w * 64;
#pragma unroll
            for (int mf = 0; mf < 4; ++mf) {
                const size_t rbase = (size_t)(rowb + mf * 16 + rlo) * NC + n0 + g * 4;
#pragma unroll
                for (int nf = 0; nf < 4; ++nf) {
                    u16x4 v;
                    v[0] = f2bf(acc[mf][nf][0]); v[1] = f2bf(acc[mf][nf][1]);
                    v[2] = f2bf(acc[mf][nf][2]); v[3] = f2bf(acc[mf][nf][3]);
                    *(u16x4*)(&C[rbase + nf * 16]) = v;
                }
            }
        }
    }
}

// ---- chunk-parallel SRU scan, plane-major U ----
template <int NC>
__global__ __launch_bounds__(256) void scanA(const unsigned short* __restrict__ U,
                                             const float* __restrict__ bias,
                                             float* __restrict__ aArr,
                                             float* __restrict__ bArr,
                                             int dirbase, int dbstride,
                                             int chmask, int chshift, int T) {
    const int gid = blockIdx.x * 256 + threadIdx.x;
    const int fc = gid & chmask;
    const int q = gid >> chshift;
    const int dir = dirbase + (fc >> 13);
    const int b = (fc >> 7) & 63, h = fc & 127;
    const int dbase = (fc >> 13) * dbstride;
    const float bfb = bias[dir * HID + h];

    float aa = 1.0f, cc = 0.0f;
#pragma unroll 4
    for (int i = 0; i < SUB; ++i) {
        const int s = q * SUB + i;
        const int t = dir ? (T - 1 - s) : s;
        const size_t m = (size_t)t * NB + b;
        const float u0 = bf2f(U[m * NC + dbase + h]);
        const float u1 = bf2f(U[m * NC + dbase + 128 + h]);
        const float f = sigmoidf_(u1 + bfb);
        cc = f * cc + (1.0f - f) * u0;
        aa *= f;
    }
    const int fcg = dir * 8192 + (fc & 8191);
    aArr[(size_t)q * NCH + fcg] = aa;
    bArr[(size_t)q * NCH + fcg] = cc;
}

template <int Q>
__global__ __launch_bounds__(256) void scanB(const float* __restrict__ aArr,
                                             const float* __restrict__ bArr,
                                             float* __restrict__ cin,
                                             float* __restrict__ carry,
                                             int init, int fcg0) {
    const int fcg = fcg0 + blockIdx.x * 256 + threadIdx.x;
    float a[Q], bb[Q];
#pragma unroll
    for (int q = 0; q < Q; ++q) {
        a[q]  = aArr[(size_t)q * NCH + fcg];
        bb[q] = bArr[(size_t)q * NCH + fcg];
    }
    float c = init ? 0.0f : carry[fcg];
#pragma unroll
    for (int q = 0; q < Q; ++q) {
        cin[(size_t)q * NCH + fcg] = c;
        c = a[q] * c + bb[q];
    }
    carry[fcg] = c;
}

template <int NC, bool XP_FROM_U, bool ACC>
__global__ __launch_bounds__(256) void scanC(const unsigned short* __restrict__ U,
                                             const unsigned short* __restrict__ Xprev,
                                             const float* __restrict__ bias,
                                             const float* __restrict__ cin,
                                             unsigned short* __restrict__ Xout,
                                             float* __restrict__ part,
                                             int dirbase, int dbstride,
                                             int chmask, int chshift,
                                             int T, int t0, int qg0) {
    const int gid = blockIdx.x * 256 + threadIdx.x;
    const int fc = gid & chmask;
    const int q = gid >> chshift;
    const int dir = dirbase + (fc >> 13);
    const int b = (fc >> 7) & 63, h = fc & 127;
    const int dbase = (fc >> 13) * dbstride;
    const float bfb = bias[dir * HID + h];
    const float brb = bias[2 * HID + dir * HID + h];
    const int fcg = dir * 8192 + (fc & 8191);

    float c = cin[(size_t)q * NCH + fcg];
    float psum = 0.0f;
#pragma unroll 4
    for (int i = 0; i < SUB; ++i) {
        const int s = q * SUB + i;
        const int t = dir ? (T - 1 - s) : s;
        const size_t m = (size_t)t * NB + b;
        const size_t xrow = ((size_t)(t0 + t) * NB + b) * (2 * HID) + dir * HID + h;
        const float u0 = bf2f(U[m * NC + dbase + h]);
        const float u1 = bf2f(U[m * NC + dbase + 128 + h]);
        const float u2 = bf2f(U[m * NC + dbase + 256 + h]);
        float xp;
        if constexpr (XP_FROM_U) xp = bf2f(U[m * NC + dbase + 384 + h]);
        else                     xp = bf2f(Xprev[xrow]);
        const float f = sigmoidf_(u1 + bfb);
        const float r = sigmoidf_(u2 + brb);
        c = f * c + (1.0f - f) * u0;
        const float ho = r * seluf_(c) + (1.0f - r) * xp;
        if constexpr (ACC) psum += ho;
        else               Xout[xrow] = f2bf(ho);
    }
    if constexpr (ACC)
        part[(size_t)(qg0 + q) * (NB * 256) + b * 256 + dir * HID + h] = psum;
}

__global__ __launch_bounds__(256) void pool2(const float* __restrict__ part,
                                             const float* __restrict__ gamma,
                                             const float* __restrict__ beta,
                                             float* __restrict__ out) {
    const int b = blockIdx.x, chn = threadIdx.x;
    float s = 0.0f;
#pragma unroll
    for (int i = 0; i < NQG; ++i) s += part[(size_t)i * (NB * 256) + b * 256 + chn];
    const float feat = s * (1.0f / LSEQ);
    __shared__ float red[256];
    red[chn] = feat; __syncthreads();
    for (int off = 128; off > 0; off >>= 1) { if (chn < off) red[chn] += red[chn + off]; __syncthreads(); }
    const float mu = red[0] * (1.0f / 256.0f);
    __syncthreads();
    const float d = feat - mu;
    red[chn] = d * d; __syncthreads();
    for (int off = 128; off > 0; off >>= 1) { if (chn < off) red[chn] += red[chn + off]; __syncthreads(); }
    const float var = red[0] * (1.0f / 256.0f);
    out[b * 256 + chn] = d * rsqrtf(var + 1e-5f) * gamma[chn] + beta[chn];
}

extern "C" void kernel_launch(void* const* d_in, const int* in_sizes, int n_in,
                              void* d_out, int out_size, void* d_ws, size_t ws_size,
                              hipStream_t stream) {
    const float* input = (const float*)d_in[0];
    const float* gamma = (const float*)d_in[3];
    const float* beta  = (const float*)d_in[4];
    const float* Wl[4] = { (const float*)d_in[1], (const float*)d_in[5],
                           (const float*)d_in[7], (const float*)d_in[9] };
    const float* bl[4] = { (const float*)d_in[2], (const float*)d_in[6],
                           (const float*)d_in[8], (const float*)d_in[10] };
    float* out = (float*)d_out;

    char* base = (char*)d_ws;
    size_t off = 0;
    auto alloc = [&](size_t bytes) { size_t o = off; off = (off + bytes + 255) & ~(size_t)255; return o; };

    unsigned short* Wt[4];
    Wt[0] = (unsigned short*)(base + alloc((size_t)1024 * 128 * 2));
    for (int i = 1; i < 4; ++i) Wt[i] = (unsigned short*)(base + alloc((size_t)768 * 256 * 2));
    unsigned short* Xa = (unsigned short*)(base + alloc((size_t)LSEQ * NB * 256 * 2));
    unsigned short* Xb = (unsigned short*)(base + alloc((size_t)LSEQ * NB * 256 * 2));
    unsigned short* Xc = (unsigned short*)(base + alloc((size_t)LSEQ * NB * 128 * 2));
    float* carry = (float*)(base + alloc((size_t)NCH * 4));
    float* aArr  = (float*)(base + alloc((size_t)32 * NCH * 4));
    float* bArr  = (float*)(base + alloc((size_t)32 * NCH * 4));
    float* cinArr= (float*)(base + alloc((size_t)32 * NCH * 4));
    float* part  = (float*)(base + alloc((size_t)NQG * NB * 256 * 4));
    if (ws_size < off + (1u << 21)) return;
    const size_t uavail = ws_size - off;
    unsigned short* U = (unsigned short*)(base + off);

    conv_in<<<(LSEQ * NB * 128 / 4 + 255) / 256, 256, 0, stream>>>(input, Xc, LSEQ * NB * 128 / 4);
    conv_wt<<<(128 * 1024 + 255) / 256, 256, 0, stream>>>(Wl[0], Wt[0], 128, 1024, 4);
    for (int i = 1; i < 4; ++i)
        conv_wt<<<(256 * 768 + 255) / 256, 256, 0, stream>>>(Wl[i], Wt[i], 256, 768, 3);

    const unsigned short* Xin[4] = { Xc, Xa, Xb, Xa };
    unsigned short* Xout[4] = { Xa, Xb, Xa, nullptr };

    if (uavail >= (size_t)LSEQ * NB * 1024 * 2) {
        // ---- merged-dir path: T=1024, one GEMM + one scanA/B/C per layer ----
        const int T = LSEQ, Q = T / SUB;  // Q = 32
        const dim3 sgrid(NCH * Q / 256);
        for (int layer = 0; layer < 4; ++layer) {
            const int kw = (layer == 0) ? 4 : 3;
            const int dbstride = 128 * kw;
            if (layer == 0)
                gemm_v8<128, 1024><<<dim3(16 * 128), 256, 0, stream>>>(Xin[0], Wt[0], U);
            else
                gemm_v8<256, 768><<<dim3(12 * 128), 256, 0, stream>>>(Xin[layer], Wt[layer], U);
            if (layer == 0)
                scanA<1024><<<sgrid, 256, 0, stream>>>(U, bl[0], aArr, bArr, 0, dbstride,
                                                       NCH - 1, 14, T);
            else
                scanA<768><<<sgrid, 256, 0, stream>>>(U, bl[layer], aArr, bArr, 0, dbstride,
                                                      NCH - 1, 14, T);
            scanB<32><<<NCH / 256, 256, 0, stream>>>(aArr, bArr, cinArr, carry, 1, 0);
            if (layer == 0)
                scanC<1024, true, false><<<sgrid, 256, 0, stream>>>(
                    U, nullptr, bl[0], cinArr, Xout[0], nullptr, 0, dbstride, NCH - 1, 14, T, 0, 0);
            else if (layer < 3)
                scanC<768, false, false><<<sgrid, 256, 0, stream>>>(
                    U, Xin[layer], bl[layer], cinArr, Xout[layer], nullptr, 0, dbstride,
                    NCH - 1, 14, T, 0, 0);
            else
                scanC<768, false, true><<<sgrid, 256, 0, stream>>>(
                    U, Xin[3], bl[3], cinArr, nullptr, part, 0, dbstride, NCH - 1, 14, T, 0, 0);
        }
    } else {
        // ---- fallback: per-dir GEMM + scans, largest T that fits (per-dir kw=4) ----
        int T = 0;
        for (int t = 512; t >= 64; t >>= 1)
            if ((size_t)t * NB * 512 * 2 <= uavail) { T = t; break; }
        if (T == 0) return;
        const int C = LSEQ / T, Q = T / SUB;
        const int nmg = T * NB / 512;
        const dim3 sgrid(8192 * Q / 256);
        for (int layer = 0; layer < 4; ++layer) {
            const int kw = (layer == 0) ? 4 : 3;
            const int K = (layer == 0) ? 128 : 256;
            const int Nc = 128 * kw;
            for (int dir = 0; dir < 2; ++dir) {
                const unsigned short* Bts = Wt[layer] + (size_t)dir * Nc * K;
                for (int cc = 0; cc < C; ++cc) {
                    const int ci = dir ? (C - 1 - cc) : cc;
                    const unsigned short* Ap = Xin[layer] + (size_t)ci * T * NB * K;
                    if (layer == 0)
                        gemm_v8<128, 512><<<dim3(8 * nmg), 256, 0, stream>>>(Ap, Bts, U);
                    else
                        gemm_v8<256, 384><<<dim3(6 * nmg), 256, 0, stream>>>(Ap, Bts, U);
                    if (layer == 0)
                        scanA<512><<<sgrid, 256, 0, stream>>>(U, bl[0], aArr, bArr, dir, 0,
                                                              8191, 13, T);
                    else
                        scanA<384><<<sgrid, 256, 0, stream>>>(U, bl[layer], aArr, bArr, dir, 0,
                                                              8191, 13, T);
                    if (Q == 16)
                        scanB<16><<<32, 256, 0, stream>>>(aArr, bArr, cinArr, carry,
                                                          cc == 0 ? 1 : 0, dir * 8192);
                    else
                        scanB<32><<<32, 256, 0, stream>>>(aArr, bArr, cinArr, carry,
                                                          cc == 0 ? 1 : 0, dir * 8192);
                    if (layer == 0)
                        scanC<512, true, false><<<sgrid, 256, 0, stream>>>(
                            U, nullptr, bl[0], cinArr, Xout[0], nullptr, dir, 0,
                            8191, 13, T, ci * T, ci * Q);
                    else if (layer < 3)
                        scanC<384, false, false><<<sgrid, 256, 0, stream>>>(
                            U, Xin[layer], bl[layer], cinArr, Xout[layer], nullptr, dir, 0,
                            8191, 13, T, ci * T, ci * Q);
                    else
                        scanC<384, false, true><<<sgrid, 256, 0, stream>>>(
                            U, Xin[3], bl[3], cinArr, nullptr, part, dir, 0,
                            8191, 13, T, ci * T, ci * Q);
                }
            }
        }
    }
    pool2<<<NB, 256, 0, stream>>>(part, gamma, beta, out);
}

// Round 15
// 415.698 us; speedup vs baseline: 1.1492x; 1.1492x over previous
//
#include <hip/hip_runtime.h>
#include <math.h>

#define HID 128
#define LSEQ 1024
#define NB 64  // batch
#define SUB 32           // subchunk length for chunk-parallel scan
#define NQG (LSEQ / SUB) // 32 time-subchunks per direction
#define NCH 16384        // total channels (2 dirs * 64 b * 128 h)

typedef __attribute__((ext_vector_type(4))) float f32x4;
typedef __attribute__((ext_vector_type(8))) short bf16x8;
typedef __attribute__((ext_vector_type(8))) unsigned short u16x8;
typedef __attribute__((ext_vector_type(4))) unsigned short u16x4;

__device__ __forceinline__ unsigned short f2bf(float x) {
    union { float f; unsigned int u; } a; a.f = x;
    unsigned int r = a.u + 0x7FFFu + ((a.u >> 16) & 1u);
    return (unsigned short)(r >> 16);
}
__device__ __forceinline__ float bf2f(unsigned short h) {
    union { float f; unsigned int u; } a; a.u = ((unsigned int)h) << 16;
    return a.f;
}
__device__ __forceinline__ float sigmoidf_(float x) { return 1.0f / (1.0f + __expf(-x)); }
__device__ __forceinline__ float seluf_(float x) {
    const float sc = 1.0507009873554805f, al = 1.6732632423543772f;
    return x > 0.0f ? sc * x : sc * al * (__expf(x) - 1.0f);
}

__device__ __forceinline__ void gload16(const unsigned short* g, unsigned short* l) {
    __builtin_amdgcn_global_load_lds(
        (const __attribute__((address_space(1))) unsigned int*)g,
        (__attribute__((address_space(3))) unsigned int*)l, 16, 0, 0);
}

// W (K x N fp32, N = 2*128*kw) -> Wt plane-major: row n' = dir*128*kw + j*128 + h
__global__ __launch_bounds__(256) void conv_wt(const float* __restrict__ W,
                                               unsigned short* __restrict__ Wt,
                                               int K, int N, int kw) {
    int idx = blockIdx.x * 256 + threadIdx.x;
    if (idx >= K * N) return;
    int k = idx / N, n = idx - k * N;
    const int dir = n / (128 * kw);
    const int rem = n - dir * 128 * kw;
    const int h = rem / kw, j = rem - h * kw;
    const int np = dir * 128 * kw + j * 128 + h;
    Wt[(size_t)np * K + k] = f2bf(W[idx]);
}

__global__ __launch_bounds__(256) void conv_in(const float* __restrict__ in,
                                               unsigned short* __restrict__ outp,
                                               int n4) {
    int idx = blockIdx.x * 256 + threadIdx.x;
    if (idx >= n4) return;
    const float4 v = *reinterpret_cast<const float4*>(in + (size_t)idx * 4);
    u16x4 w;
    w[0] = f2bf(v.x); w[1] = f2bf(v.y); w[2] = f2bf(v.z); w[3] = f2bf(v.w);
    *(u16x4*)(outp + (size_t)idx * 4) = w;
}

// Streaming GEMM v9 = v7 inner structure + 128-col n-tile (v5's A-reuse).
// Rationale (r8 vs r13 totals): 64-col tiles stream A 12x (402 MB) through L3
// and evict U before the scans read it (scan time doubled). 128-col tile halves
// the A stream (6x, ~200 MB) so U stays L3-resident for the scans.
// Block: 128-col n-tile, B resident in LDS (64 KB, loaded once), 4 m-tiles of
// 128 rows. Wave = 32 rows; per step: 4 A reg-loads (depth-1) + 16 ds_read +
// 32 MFMA; barrier-free main loop; swapped-operand MFMA -> direct 8B stores.
template <int K, int NC>
__global__ __launch_bounds__(256, 2) void gemm_v9(const unsigned short* __restrict__ A,
                                                  const unsigned short* __restrict__ Bt,
                                                  unsigned short* __restrict__ C) {
    constexpr int NN = NC / 128;
    constexpr int NT = K / 64;
    constexpr int NSTEP = 4 * NT;  // 4 m-tiles of 128 rows per block
    __shared__ __align__(16) unsigned short smB[NT * 8192];  // 128 cols x K

    const int bid = blockIdx.x;
    const int mi = bid & 7;                 // XCD index
    const int tt = bid >> 3;
    const int n = tt % NN;
    const int mg = (tt / NN) * 8 + mi;
    const int mb = mg * 512;
    const int n0 = n * 128;

    const int tid = threadIdx.x;
    const int w = tid >> 6, l = tid & 63;
    const int rlo = l & 15, g = l >> 4;
    const int kswz = (rlo & 7) * 8;

    // ---- B resident load (once): 128 cols x K, swizzled k-chunks ----
#pragma unroll
    for (int kt = 0; kt < NT; ++kt)
#pragma unroll
        for (int cc = 0; cc < 4; ++cc) {
            const int col = cc * 32 + (tid >> 3);
            const int kxb = (tid & 7) ^ ((tid >> 3) & 7);
            gload16(Bt + (size_t)(n0 + col) * K + kt * 64 + kxb * 8,
                    &smB[kt * 8192 + cc * 2048 + tid * 8]);
        }

    // per-lane A base: row = mb + w*32 + rlo, k-chunk g*8
    const unsigned short* gA = A + ((size_t)mb + w * 32 + rlo) * K + g * 8;

    bf16x8 af[2][2][2];  // [buf][mf][kk] — static indices after unroll
    auto loadA = [&](int s, int buf) {
        const int mt = s / NT, kt = s % NT;
        const unsigned short* p = gA + (size_t)mt * 128 * K + kt * 64;
#pragma unroll
        for (int mf = 0; mf < 2; ++mf)
#pragma unroll
            for (int kk = 0; kk < 2; ++kk)
                af[buf][mf][kk] = *(const bf16x8*)(p + (size_t)mf * 16 * K + kk * 32);
    };

    loadA(0, 0);
    __syncthreads();  // B resident for all waves (prologue-only full drain)

    f32x4 acc[2][8];
#pragma unroll
    for (int s = 0; s < NSTEP; ++s) {
        const int mt = s / NT, kt = s % NT, cur = s & 1;
        if (kt == 0) {
#pragma unroll
            for (int mf = 0; mf < 2; ++mf)
#pragma unroll
                for (int nf = 0; nf < 8; ++nf) acc[mf][nf] = (f32x4){0.f, 0.f, 0.f, 0.f};
        }
        if (s + 1 < NSTEP) loadA(s + 1, cur ^ 1);  // depth-1 reg prefetch
#pragma unroll
        for (int kk = 0; kk < 2; ++kk) {
            const int koff = (kk * 32 + g * 8) ^ kswz;
            bf16x8 bff[8];
#pragma unroll
            for (int nf = 0; nf < 8; ++nf)
                bff[nf] = *(const bf16x8*)(&smB[kt * 8192 + (nf * 16 + rlo) * 64 + koff]);
#pragma unroll
            for (int mf = 0; mf < 2; ++mf)
#pragma unroll
                for (int nf = 0; nf < 8; ++nf)
                    acc[mf][nf] = __builtin_amdgcn_mfma_f32_16x16x32_bf16(
                        bff[nf], af[cur][mf][kk], acc[mf][nf], 0, 0, 0);  // swapped
        }
        if (kt == NT - 1) {  // lane holds rows ...+rlo, cols nf*16 + g*4 .. +3
            const int rowb = mb + mt * 128 + w * 32;
#pragma unroll
            for (int mf = 0; mf < 2; ++mf) {
                const size_t rbase = (size_t)(rowb + mf * 16 + rlo) * NC + n0 + g * 4;
#pragma unroll
                for (int nf = 0; nf < 8; ++nf) {
                    u16x4 v;
                    v[0] = f2bf(acc[mf][nf][0]); v[1] = f2bf(acc[mf][nf][1]);
                    v[2] = f2bf(acc[mf][nf][2]); v[3] = f2bf(acc[mf][nf][3]);
                    *(u16x4*)(&C[rbase + nf * 16]) = v;
                }
            }
        }
    }
}

// ---- chunk-parallel SRU scan, plane-major U ----
template <int NC>
__global__ __launch_bounds__(256) void scanA(const unsigned short* __restrict__ U,
                                             const float* __restrict__ bias,
                                             float* __restrict__ aArr,
                                             float* __restrict__ bArr,
                                             int dirbase, int dbstride,
                                             int chmask, int chshift, int T) {
    const int gid = blockIdx.x * 256 + threadIdx.x;
    const int fc = gid & chmask;
    const int q = gid >> chshift;
    const int dir = dirbase + (fc >> 13);
    const int b = (fc >> 7) & 63, h = fc & 127;
    const int dbase = (fc >> 13) * dbstride;
    const float bfb = bias[dir * HID + h];

    float aa = 1.0f, cc = 0.0f;
#pragma unroll 4
    for (int i = 0; i < SUB; ++i) {
        const int s = q * SUB + i;
        const int t = dir ? (T - 1 - s) : s;
        const size_t m = (size_t)t * NB + b;
        const float u0 = bf2f(U[m * NC + dbase + h]);
        const float u1 = bf2f(U[m * NC + dbase + 128 + h]);
        const float f = sigmoidf_(u1 + bfb);
        cc = f * cc + (1.0f - f) * u0;
        aa *= f;
    }
    const int fcg = dir * 8192 + (fc & 8191);
    aArr[(size_t)q * NCH + fcg] = aa;
    bArr[(size_t)q * NCH + fcg] = cc;
}

template <int Q>
__global__ __launch_bounds__(256) void scanB(const float* __restrict__ aArr,
                                             const float* __restrict__ bArr,
                                             float* __restrict__ cin,
                                             float* __restrict__ carry,
                                             int init, int fcg0) {
    const int fcg = fcg0 + blockIdx.x * 256 + threadIdx.x;
    float a[Q], bb[Q];
#pragma unroll
    for (int q = 0; q < Q; ++q) {
        a[q]  = aArr[(size_t)q * NCH + fcg];
        bb[q] = bArr[(size_t)q * NCH + fcg];
    }
    float c = init ? 0.0f : carry[fcg];
#pragma unroll
    for (int q = 0; q < Q; ++q) {
        cin[(size_t)q * NCH + fcg] = c;
        c = a[q] * c + bb[q];
    }
    carry[fcg] = c;
}

template <int NC, bool XP_FROM_U, bool ACC>
__global__ __launch_bounds__(256) void scanC(const unsigned short* __restrict__ U,
                                             const unsigned short* __restrict__ Xprev,
                                             const float* __restrict__ bias,
                                             const float* __restrict__ cin,
                                             unsigned short* __restrict__ Xout,
                                             float* __restrict__ part,
                                             int dirbase, int dbstride,
                                             int chmask, int chshift,
                                             int T, int t0, int qg0) {
    const int gid = blockIdx.x * 256 + threadIdx.x;
    const int fc = gid & chmask;
    const int q = gid >> chshift;
    const int dir = dirbase + (fc >> 13);
    const int b = (fc >> 7) & 63, h = fc & 127;
    const int dbase = (fc >> 13) * dbstride;
    const float bfb = bias[dir * HID + h];
    const float brb = bias[2 * HID + dir * HID + h];
    const int fcg = dir * 8192 + (fc & 8191);

    float c = cin[(size_t)q * NCH + fcg];
    float psum = 0.0f;
#pragma unroll 4
    for (int i = 0; i < SUB; ++i) {
        const int s = q * SUB + i;
        const int t = dir ? (T - 1 - s) : s;
        const size_t m = (size_t)t * NB + b;
        const size_t xrow = ((size_t)(t0 + t) * NB + b) * (2 * HID) + dir * HID + h;
        const float u0 = bf2f(U[m * NC + dbase + h]);
        const float u1 = bf2f(U[m * NC + dbase + 128 + h]);
        const float u2 = bf2f(U[m * NC + dbase + 256 + h]);
        float xp;
        if constexpr (XP_FROM_U) xp = bf2f(U[m * NC + dbase + 384 + h]);
        else                     xp = bf2f(Xprev[xrow]);
        const float f = sigmoidf_(u1 + bfb);
        const float r = sigmoidf_(u2 + brb);
        c = f * c + (1.0f - f) * u0;
        const float ho = r * seluf_(c) + (1.0f - r) * xp;
        if constexpr (ACC) psum += ho;
        else               Xout[xrow] = f2bf(ho);
    }
    if constexpr (ACC)
        part[(size_t)(qg0 + q) * (NB * 256) + b * 256 + dir * HID + h] = psum;
}

__global__ __launch_bounds__(256) void pool2(const float* __restrict__ part,
                                             const float* __restrict__ gamma,
                                             const float* __restrict__ beta,
                                             float* __restrict__ out) {
    const int b = blockIdx.x, chn = threadIdx.x;
    float s = 0.0f;
#pragma unroll
    for (int i = 0; i < NQG; ++i) s += part[(size_t)i * (NB * 256) + b * 256 + chn];
    const float feat = s * (1.0f / LSEQ);
    __shared__ float red[256];
    red[chn] = feat; __syncthreads();
    for (int off = 128; off > 0; off >>= 1) { if (chn < off) red[chn] += red[chn + off]; __syncthreads(); }
    const float mu = red[0] * (1.0f / 256.0f);
    __syncthreads();
    const float d = feat - mu;
    red[chn] = d * d; __syncthreads();
    for (int off = 128; off > 0; off >>= 1) { if (chn < off) red[chn] += red[chn + off]; __syncthreads(); }
    const float var = red[0] * (1.0f / 256.0f);
    out[b * 256 + chn] = d * rsqrtf(var + 1e-5f) * gamma[chn] + beta[chn];
}

extern "C" void kernel_launch(void* const* d_in, const int* in_sizes, int n_in,
                              void* d_out, int out_size, void* d_ws, size_t ws_size,
                              hipStream_t stream) {
    const float* input = (const float*)d_in[0];
    const float* gamma = (const float*)d_in[3];
    const float* beta  = (const float*)d_in[4];
    const float* Wl[4] = { (const float*)d_in[1], (const float*)d_in[5],
                           (const float*)d_in[7], (const float*)d_in[9] };
    const float* bl[4] = { (const float*)d_in[2], (const float*)d_in[6],
                           (const float*)d_in[8], (const float*)d_in[10] };
    float* out = (float*)d_out;

    char* base = (char*)d_ws;
    size_t off = 0;
    auto alloc = [&](size_t bytes) { size_t o = off; off = (off + bytes + 255) & ~(size_t)255; return o; };

    unsigned short* Wt[4];
    Wt[0] = (unsigned short*)(base + alloc((size_t)1024 * 128 * 2));
    for (int i = 1; i < 4; ++i) Wt[i] = (unsigned short*)(base + alloc((size_t)768 * 256 * 2));
    unsigned short* Xa = (unsigned short*)(base + alloc((size_t)LSEQ * NB * 256 * 2));
    unsigned short* Xb = (unsigned short*)(base + alloc((size_t)LSEQ * NB * 256 * 2));
    unsigned short* Xc = (unsigned short*)(base + alloc((size_t)LSEQ * NB * 128 * 2));
    float* carry = (float*)(base + alloc((size_t)NCH * 4));
    float* aArr  = (float*)(base + alloc((size_t)32 * NCH * 4));
    float* bArr  = (float*)(base + alloc((size_t)32 * NCH * 4));
    float* cinArr= (float*)(base + alloc((size_t)32 * NCH * 4));
    float* part  = (float*)(base + alloc((size_t)NQG * NB * 256 * 4));
    if (ws_size < off + (1u << 21)) return;
    const size_t uavail = ws_size - off;
    unsigned short* U = (unsigned short*)(base + off);

    conv_in<<<(LSEQ * NB * 128 / 4 + 255) / 256, 256, 0, stream>>>(input, Xc, LSEQ * NB * 128 / 4);
    conv_wt<<<(128 * 1024 + 255) / 256, 256, 0, stream>>>(Wl[0], Wt[0], 128, 1024, 4);
    for (int i = 1; i < 4; ++i)
        conv_wt<<<(256 * 768 + 255) / 256, 256, 0, stream>>>(Wl[i], Wt[i], 256, 768, 3);

    const unsigned short* Xin[4] = { Xc, Xa, Xb, Xa };
    unsigned short* Xout[4] = { Xa, Xb, Xa, nullptr };

    if (uavail >= (size_t)LSEQ * NB * 1024 * 2) {
        // ---- merged-dir path: T=1024, one GEMM + one scanA/B/C per layer ----
        const int T = LSEQ, Q = T / SUB;  // Q = 32
        const dim3 sgrid(NCH * Q / 256);
        for (int layer = 0; layer < 4; ++layer) {
            const int kw = (layer == 0) ? 4 : 3;
            const int dbstride = 128 * kw;
            if (layer == 0)
                gemm_v9<128, 1024><<<dim3(8 * 128), 256, 0, stream>>>(Xin[0], Wt[0], U);
            else
                gemm_v9<256, 768><<<dim3(6 * 128), 256, 0, stream>>>(Xin[layer], Wt[layer], U);
            if (layer == 0)
                scanA<1024><<<sgrid, 256, 0, stream>>>(U, bl[0], aArr, bArr, 0, dbstride,
                                                       NCH - 1, 14, T);
            else
                scanA<768><<<sgrid, 256, 0, stream>>>(U, bl[layer], aArr, bArr, 0, dbstride,
                                                      NCH - 1, 14, T);
            scanB<32><<<NCH / 256, 256, 0, stream>>>(aArr, bArr, cinArr, carry, 1, 0);
            if (layer == 0)
                scanC<1024, true, false><<<sgrid, 256, 0, stream>>>(
                    U, nullptr, bl[0], cinArr, Xout[0], nullptr, 0, dbstride, NCH - 1, 14, T, 0, 0);
            else if (layer < 3)
                scanC<768, false, false><<<sgrid, 256, 0, stream>>>(
                    U, Xin[layer], bl[layer], cinArr, Xout[layer], nullptr, 0, dbstride,
                    NCH - 1, 14, T, 0, 0);
            else
                scanC<768, false, true><<<sgrid, 256, 0, stream>>>(
                    U, Xin[3], bl[3], cinArr, nullptr, part, 0, dbstride, NCH - 1, 14, T, 0, 0);
        }
    } else {
        // ---- fallback: per-dir GEMM + scans, largest T that fits (per-dir kw=4) ----
        int T = 0;
        for (int t = 512; t >= 64; t >>= 1)
            if ((size_t)t * NB * 512 * 2 <= uavail) { T = t; break; }
        if (T == 0) return;
        const int C = LSEQ / T, Q = T / SUB;
        const int nmg = T * NB / 512;
        const dim3 sgrid(8192 * Q / 256);
        for (int layer = 0; layer < 4; ++layer) {
            const int kw = (layer == 0) ? 4 : 3;
            const int K = (layer == 0) ? 128 : 256;
            const int Nc = 128 * kw;
            for (int dir = 0; dir < 2; ++dir) {
                const unsigned short* Bts = Wt[layer] + (size_t)dir * Nc * K;
                for (int cc = 0; cc < C; ++cc) {
                    const int ci = dir ? (C - 1 - cc) : cc;
                    const unsigned short* Ap = Xin[layer] + (size_t)ci * T * NB * K;
                    if (layer == 0)
                        gemm_v9<128, 512><<<dim3(4 * nmg), 256, 0, stream>>>(Ap, Bts, U);
                    else
                        gemm_v9<256, 384><<<dim3(3 * nmg), 256, 0, stream>>>(Ap, Bts, U);
                    if (layer == 0)
                        scanA<512><<<sgrid, 256, 0, stream>>>(U, bl[0], aArr, bArr, dir, 0,
                                                              8191, 13, T);
                    else
                        scanA<384><<<sgrid, 256, 0, stream>>>(U, bl[layer], aArr, bArr, dir, 0,
                                                              8191, 13, T);
                    if (Q == 16)
                        scanB<16><<<32, 256, 0, stream>>>(aArr, bArr, cinArr, carry,
                                                          cc == 0 ? 1 : 0, dir * 8192);
                    else
                        scanB<32><<<32, 256, 0, stream>>>(aArr, bArr, cinArr, carry,
                                                          cc == 0 ? 1 : 0, dir * 8192);
                    if (layer == 0)
                        scanC<512, true, false><<<sgrid, 256, 0, stream>>>(
                            U, nullptr, bl[0], cinArr, Xout[0], nullptr, dir, 0,
                            8191, 13, T, ci * T, ci * Q);
                    else if (layer < 3)
                        scanC<384, false, false><<<sgrid, 256, 0, stream>>>(
                            U, Xin[layer], bl[layer], cinArr, Xout[layer], nullptr, dir, 0,
                            8191, 13, T, ci * T, ci * Q);
                    else
                        scanC<384, false, true><<<sgrid, 256, 0, stream>>>(
                            U, Xin[3], bl[3], cinArr, nullptr, part, dir, 0,
                            8191, 13, T, ci * T, ci * Q);
                }
            }
        }
    }
    pool2<<<NB, 256, 0, stream>>>(part, gamma, beta, out);
}